// Round 1
// baseline (1136.195 us; speedup 1.0000x reference)
//
#include <hip/hip_runtime.h>

#define N_NODES 100000
#define N_EDGES 3200000
#define N_GRAPHS 1024
#define HID 32
#define BN_EPS 1e-5f

// ---------------- kernels ----------------

__global__ void k_init(float* __restrict__ deg, float* __restrict__ sums,
                       float* __restrict__ cnt) {
    int i = blockIdx.x * blockDim.x + threadIdx.x;
    if (i < N_NODES) deg[i] = 1.0f;                 // self-loop contributes 1
    if (i < N_GRAPHS * HID) sums[i] = 0.0f;
    if (i < N_GRAPHS) cnt[i] = 0.0f;
}

__global__ void k_deg(const int* __restrict__ dst, float* __restrict__ deg) {
    int e = blockIdx.x * blockDim.x + threadIdx.x;
    if (e < N_EDGES) atomicAdd(&deg[dst[e]], 1.0f);
}

// dinv, layer-1 self-loop term, per-graph node counts
__global__ void k_dinv_s0(const float* __restrict__ deg, const float* __restrict__ x,
                          const int* __restrict__ batch, float* __restrict__ dinv,
                          float* __restrict__ s, float* __restrict__ cnt) {
    int i = blockIdx.x * blockDim.x + threadIdx.x;
    if (i < N_NODES) {
        float di = rsqrtf(deg[i]);   // deg >= 1 always (self-loop)
        dinv[i] = di;
        s[i] = di * di * x[i];
        atomicAdd(&cnt[batch[i]], 1.0f);
    }
}

// layer-1 edge aggregation (scalar feature)
__global__ void k_agg1(const int* __restrict__ src, const int* __restrict__ dst,
                       const float* __restrict__ dinv, const float* __restrict__ x,
                       float* __restrict__ s) {
    int e = blockIdx.x * blockDim.x + threadIdx.x;
    if (e < N_EDGES) {
        int u = src[e], v = dst[e];
        atomicAdd(&s[v], dinv[u] * dinv[v] * x[u]);
    }
}

// z1 = relu(bn1(s*W1 + b1)); agg2 initialized with self-loop term
__global__ void k_l1post(const float* __restrict__ s, const float* __restrict__ W1,
                         const float* __restrict__ b1, const float* __restrict__ g,
                         const float* __restrict__ bb, const float* __restrict__ m,
                         const float* __restrict__ v, const float* __restrict__ dinv,
                         float* __restrict__ z1, float* __restrict__ agg2) {
    int t = blockIdx.x * blockDim.x + threadIdx.x;
    if (t < N_NODES * HID) {
        int i = t >> 5, f = t & 31;
        float h = s[i] * W1[f] + b1[f];
        float scale = g[f] * rsqrtf(v[f] + BN_EPS);
        float z = fmaxf((h - m[f]) * scale + bb[f], 0.0f);
        z1[t] = z;
        float di = dinv[i];
        agg2[t] = di * di * z;
    }
}

// edge aggregation over 32 features: lane = feature -> contiguous 128B per edge
__global__ void k_aggF(const int* __restrict__ src, const int* __restrict__ dst,
                       const float* __restrict__ dinv, const float* __restrict__ zin,
                       float* __restrict__ aggout) {
    int t = blockIdx.x * blockDim.x + threadIdx.x;   // E*32 = 102.4M < 2^31
    if (t < N_EDGES * HID) {
        int e = t >> 5, f = t & 31;
        int u = src[e], v = dst[e];
        float nrm = dinv[u] * dinv[v];
        atomicAdd(&aggout[v * HID + f], nrm * zin[u * HID + f]);
    }
}

// z = relu(bn(agg @ W + b)); aggnext initialized with self-loop term
__global__ void k_l2post(const float* __restrict__ agg, const float* __restrict__ W,
                         const float* __restrict__ b, const float* __restrict__ g,
                         const float* __restrict__ bb, const float* __restrict__ m,
                         const float* __restrict__ v, const float* __restrict__ dinv,
                         float* __restrict__ z, float* __restrict__ aggnext) {
    __shared__ float Ws[HID * HID];
    for (int k = threadIdx.x; k < HID * HID; k += blockDim.x) Ws[k] = W[k];
    __syncthreads();
    int t = blockIdx.x * blockDim.x + threadIdx.x;
    if (t < N_NODES * HID) {
        int i = t >> 5, f = t & 31;
        const float* row = &agg[i * HID];
        float acc = b[f];
#pragma unroll
        for (int k = 0; k < HID; ++k) acc += row[k] * Ws[k * HID + f];
        float scale = g[f] * rsqrtf(v[f] + BN_EPS);
        float zz = fmaxf((acc - m[f]) * scale + bb[f], 0.0f);
        z[t] = zz;
        float di = dinv[i];
        aggnext[t] = di * di * zz;
    }
}

// h3 = agg3 @ W3 + b3, pooled into per-graph sums
__global__ void k_l3pool(const float* __restrict__ agg, const float* __restrict__ W,
                         const float* __restrict__ b, const int* __restrict__ batch,
                         float* __restrict__ sums) {
    __shared__ float Ws[HID * HID];
    for (int k = threadIdx.x; k < HID * HID; k += blockDim.x) Ws[k] = W[k];
    __syncthreads();
    int t = blockIdx.x * blockDim.x + threadIdx.x;
    if (t < N_NODES * HID) {
        int i = t >> 5, f = t & 31;
        const float* row = &agg[i * HID];
        float acc = b[f];
#pragma unroll
        for (int k = 0; k < HID; ++k) acc += row[k] * Ws[k * HID + f];
        atomicAdd(&sums[batch[i] * HID + f], acc);
    }
}

__global__ void k_final(const float* __restrict__ sums, const float* __restrict__ cnt,
                        float* __restrict__ out) {
    int t = blockIdx.x * blockDim.x + threadIdx.x;
    if (t < N_GRAPHS * HID) {
        int gi = t >> 5;
        out[t] = sums[t] / fmaxf(cnt[gi], 1.0f);
    }
}

// ---------------- launch ----------------

extern "C" void kernel_launch(void* const* d_in, const int* in_sizes, int n_in,
                              void* d_out, int out_size, void* d_ws, size_t ws_size,
                              hipStream_t stream) {
    const float* x     = (const float*)d_in[0];
    const int*   eidx  = (const int*)d_in[1];     // [2, E]: row0 = src, row1 = dst
    const int*   batch = (const int*)d_in[2];
    const float* W1    = (const float*)d_in[3];
    const float* b1    = (const float*)d_in[4];
    const float* bn1g  = (const float*)d_in[5];
    const float* bn1b  = (const float*)d_in[6];
    const float* bn1m  = (const float*)d_in[7];
    const float* bn1v  = (const float*)d_in[8];
    const float* W2    = (const float*)d_in[9];
    const float* b2    = (const float*)d_in[10];
    const float* bn2g  = (const float*)d_in[11];
    const float* bn2b  = (const float*)d_in[12];
    const float* bn2m  = (const float*)d_in[13];
    const float* bn2v  = (const float*)d_in[14];
    const float* W3    = (const float*)d_in[15];
    const float* b3    = (const float*)d_in[16];
    float* out = (float*)d_out;

    const int* src = eidx;
    const int* dst = eidx + N_EDGES;

    // workspace carving (256B aligned)
    char* ws = (char*)d_ws;
    size_t off = 0;
    auto carve = [&](size_t bytes) {
        void* p = ws + off;
        off += (bytes + 255) & ~size_t(255);
        return p;
    };
    float* deg  = (float*)carve(N_NODES * 4);
    float* dinv = (float*)carve(N_NODES * 4);
    float* s    = (float*)carve(N_NODES * 4);
    float* z1   = (float*)carve((size_t)N_NODES * HID * 4);
    float* agg2 = (float*)carve((size_t)N_NODES * HID * 4);
    float* z2   = (float*)carve((size_t)N_NODES * HID * 4);
    float* sums = (float*)carve(N_GRAPHS * HID * 4);
    float* cnt  = (float*)carve(N_GRAPHS * 4);
    float* agg3 = z1;   // z1 is dead after layer-2 aggregation; reuse

    const int B = 256;
    const int gN   = (N_NODES + B - 1) / B;
    const int gE   = (N_EDGES + B - 1) / B;
    const int gNF  = (N_NODES * HID + B - 1) / B;
    const int gEF  = (N_EDGES * HID + B - 1) / B;     // 400,000 blocks
    const int gOut = (N_GRAPHS * HID + B - 1) / B;

    k_init<<<gN, B, 0, stream>>>(deg, sums, cnt);
    k_deg<<<gE, B, 0, stream>>>(dst, deg);
    k_dinv_s0<<<gN, B, 0, stream>>>(deg, x, batch, dinv, s, cnt);
    k_agg1<<<gE, B, 0, stream>>>(src, dst, dinv, x, s);
    k_l1post<<<gNF, B, 0, stream>>>(s, W1, b1, bn1g, bn1b, bn1m, bn1v, dinv, z1, agg2);
    k_aggF<<<gEF, B, 0, stream>>>(src, dst, dinv, z1, agg2);
    k_l2post<<<gNF, B, 0, stream>>>(agg2, W2, b2, bn2g, bn2b, bn2m, bn2v, dinv, z2, agg3);
    k_aggF<<<gEF, B, 0, stream>>>(src, dst, dinv, z2, agg3);
    k_l3pool<<<gNF, B, 0, stream>>>(agg3, W3, b3, batch, sums);
    k_final<<<gOut, B, 0, stream>>>(sums, cnt, out);
}

// Round 2
// 785.259 us; speedup vs baseline: 1.4469x; 1.4469x over previous
//
#include <hip/hip_runtime.h>

#define N_NODES 100000
#define N_EDGES 3200000
#define N_GRAPHS 1024
#define HID 32
#define BN_EPS 1e-5f
#define NB 256

// ---------------- helpers ----------------

__device__ __forceinline__ int lbound(const int* __restrict__ a, int n, int key) {
    int lo = 0, hi = n;
    while (lo < hi) {
        int mid = (lo + hi) >> 1;
        if (a[mid] < key) lo = mid + 1; else hi = mid;
    }
    return lo;
}

// ---------------- CSR build ----------------

__global__ void k_zero_deg(int* __restrict__ deg) {
    int i = blockIdx.x * NB + threadIdx.x;
    if (i < N_NODES) deg[i] = 0;
}

__global__ void k_deg(const int* __restrict__ dst, int* __restrict__ deg) {
    int e = blockIdx.x * NB + threadIdx.x;
    if (e < N_EDGES) atomicAdd(&deg[dst[e]], 1);
}

// per-block sums of deg
__global__ void k_scanA(const int* __restrict__ deg, int* __restrict__ bsum) {
    __shared__ int sm[NB];
    int i = blockIdx.x * NB + threadIdx.x;
    int t = threadIdx.x;
    sm[t] = (i < N_NODES) ? deg[i] : 0;
    __syncthreads();
    for (int s = NB / 2; s > 0; s >>= 1) {
        if (t < s) sm[t] += sm[t + s];
        __syncthreads();
    }
    if (t == 0) bsum[blockIdx.x] = sm[0];
}

// exclusive scan of block sums (n <= 512), single block of 512
__global__ void k_scanB(int* __restrict__ bsum, int n) {
    __shared__ int sm[512];
    int t = threadIdx.x;
    int orig = (t < n) ? bsum[t] : 0;
    sm[t] = orig;
    __syncthreads();
    for (int off = 1; off < 512; off <<= 1) {
        int v = (t >= off) ? sm[t - off] : 0;
        __syncthreads();
        sm[t] += v;
        __syncthreads();
    }
    if (t < n) bsum[t] = sm[t] - orig;   // exclusive
}

// per-block exclusive scan + offset -> rowstart/cursor; also dinv, zs1
__global__ void k_scanC(const int* __restrict__ deg, const int* __restrict__ bsum,
                        const float* __restrict__ x, int* __restrict__ rowstart,
                        int* __restrict__ cursor, float* __restrict__ dinv,
                        float* __restrict__ zs1) {
    __shared__ int sm[NB];
    int i = blockIdx.x * NB + threadIdx.x;
    int t = threadIdx.x;
    int d = (i < N_NODES) ? deg[i] : 0;
    sm[t] = d;
    __syncthreads();
    for (int off = 1; off < NB; off <<= 1) {
        int v = (t >= off) ? sm[t - off] : 0;
        __syncthreads();
        sm[t] += v;
        __syncthreads();
    }
    if (i < N_NODES) {
        int rs = bsum[blockIdx.x] + sm[t] - d;   // exclusive within block + block offset
        rowstart[i] = rs;
        cursor[i] = rs;
        float di = rsqrtf((float)(d + 1));        // +1 self-loop
        dinv[i] = di;
        zs1[i] = di * x[i];
    }
}

__global__ void k_scatter(const int* __restrict__ src, const int* __restrict__ dst,
                          int* __restrict__ cursor, int* __restrict__ csr) {
    int e = blockIdx.x * NB + threadIdx.x;
    if (e < N_EDGES) {
        int v = dst[e];
        int pos = atomicAdd(&cursor[v], 1);
        csr[pos] = src[e];
    }
}

// ---------------- layer 1 (scalar feature) ----------------

__global__ void k_gather1(const int* __restrict__ rowstart, const int* __restrict__ deg,
                          const int* __restrict__ csr, const float* __restrict__ dinv,
                          const float* __restrict__ zs1, float* __restrict__ s) {
    int v = blockIdx.x * NB + threadIdx.x;
    if (v < N_NODES) {
        int lo = rowstart[v], n = deg[v];
        float acc = zs1[v];
        for (int j = 0; j < n; ++j) acc += zs1[csr[lo + j]];
        s[v] = dinv[v] * acc;
    }
}

// zs2 = dinv * relu(bn1(s*W1 + b1))
__global__ void k_l1post(const float* __restrict__ s, const float* __restrict__ W1,
                         const float* __restrict__ b1, const float* __restrict__ g,
                         const float* __restrict__ bb, const float* __restrict__ m,
                         const float* __restrict__ v, const float* __restrict__ dinv,
                         float* __restrict__ zs2) {
    int t = blockIdx.x * NB + threadIdx.x;
    if (t < N_NODES * HID) {
        int i = t >> 5, f = t & 31;
        float h = s[i] * W1[f] + b1[f];
        float scale = g[f] * rsqrtf(v[f] + BN_EPS);
        float z = fmaxf((h - m[f]) * scale + bb[f], 0.0f);
        zs2[t] = dinv[i] * z;
    }
}

// ---------------- layer 2: gather + fused matmul/BN/ReLU/prescale ----------------

__global__ void k_gather2(const int* __restrict__ rowstart, const int* __restrict__ deg,
                          const int* __restrict__ csr, const float* __restrict__ dinv,
                          const float* __restrict__ zs2, const float* __restrict__ W2,
                          const float* __restrict__ b2, const float* __restrict__ g2,
                          const float* __restrict__ bb2, const float* __restrict__ m2,
                          const float* __restrict__ v2, float* __restrict__ zs3) {
    __shared__ float Ws[HID * HID];
    __shared__ float rowbuf[NB / HID][HID + 1];
    for (int k = threadIdx.x; k < HID * HID; k += NB) Ws[k] = W2[k];

    int t = blockIdx.x * NB + threadIdx.x;
    int v = t >> 5, f = t & 31, r = threadIdx.x >> 5;
    float acc = 0.0f, di = 0.0f;
    if (v < N_NODES) {
        di = dinv[v];
        int lo = rowstart[v], n = deg[v];
        acc = zs2[v * HID + f];
        for (int j = 0; j < n; ++j) {
            int u = csr[lo + j];
            acc += zs2[u * HID + f];
        }
        acc *= di;
    }
    rowbuf[r][f] = acc;
    __syncthreads();
    if (v < N_NODES) {
        float h = b2[f];
#pragma unroll
        for (int k = 0; k < HID; ++k) h += rowbuf[r][k] * Ws[k * HID + f];
        float scale = g2[f] * rsqrtf(v2[f] + BN_EPS);
        float z = fmaxf((h - m2[f]) * scale + bb2[f], 0.0f);
        zs3[v * HID + f] = di * z;
    }
}

// ---------------- layer 3: gather only ----------------

__global__ void k_gather3(const int* __restrict__ rowstart, const int* __restrict__ deg,
                          const int* __restrict__ csr, const float* __restrict__ dinv,
                          const float* __restrict__ zs3, float* __restrict__ agg3) {
    int t = blockIdx.x * NB + threadIdx.x;
    int v = t >> 5, f = t & 31;
    if (v < N_NODES) {
        int lo = rowstart[v], n = deg[v];
        float acc = zs3[v * HID + f];
        for (int j = 0; j < n; ++j) {
            int u = csr[lo + j];
            acc += zs3[u * HID + f];
        }
        agg3[v * HID + f] = dinv[v] * acc;
    }
}

// ---------------- pool: block per graph, mean then matmul W3 ----------------

__global__ void k_pool(const float* __restrict__ agg3, const int* __restrict__ batch,
                       const float* __restrict__ W3, const float* __restrict__ b3,
                       float* __restrict__ out) {
    __shared__ float Ws[HID * HID];
    __shared__ float part[NB / HID][HID + 1];
    __shared__ float mrow[HID];
    int g = blockIdx.x;
    for (int k = threadIdx.x; k < HID * HID; k += NB) Ws[k] = W3[k];

    int lo = lbound(batch, N_NODES, g);
    int hi = lbound(batch, N_NODES, g + 1);

    int r = threadIdx.x >> 5, f = threadIdx.x & 31;
    float acc = 0.0f;
    for (int i = lo + r; i < hi; i += NB / HID) acc += agg3[i * HID + f];
    part[r][f] = acc;
    __syncthreads();
    if (threadIdx.x < HID) {
        float srow = 0.0f;
#pragma unroll
        for (int k = 0; k < NB / HID; ++k) srow += part[k][threadIdx.x];
        float c = (float)(hi - lo);
        mrow[threadIdx.x] = (hi > lo) ? srow / c : 0.0f;
    }
    __syncthreads();
    if (threadIdx.x < HID) {
        int ff = threadIdx.x;
        float o = 0.0f;
        if (hi > lo) {
            o = b3[ff];
#pragma unroll
            for (int k = 0; k < HID; ++k) o += mrow[k] * Ws[k * HID + ff];
        }
        out[g * HID + ff] = o;
    }
}

// ---------------- launch ----------------

extern "C" void kernel_launch(void* const* d_in, const int* in_sizes, int n_in,
                              void* d_out, int out_size, void* d_ws, size_t ws_size,
                              hipStream_t stream) {
    const float* x     = (const float*)d_in[0];
    const int*   eidx  = (const int*)d_in[1];     // [2, E]: row0 = src, row1 = dst
    const int*   batch = (const int*)d_in[2];
    const float* W1    = (const float*)d_in[3];
    const float* b1    = (const float*)d_in[4];
    const float* bn1g  = (const float*)d_in[5];
    const float* bn1b  = (const float*)d_in[6];
    const float* bn1m  = (const float*)d_in[7];
    const float* bn1v  = (const float*)d_in[8];
    const float* W2    = (const float*)d_in[9];
    const float* b2    = (const float*)d_in[10];
    const float* bn2g  = (const float*)d_in[11];
    const float* bn2b  = (const float*)d_in[12];
    const float* bn2m  = (const float*)d_in[13];
    const float* bn2v  = (const float*)d_in[14];
    const float* W3    = (const float*)d_in[15];
    const float* b3    = (const float*)d_in[16];
    float* out = (float*)d_out;

    const int* src = eidx;
    const int* dst = eidx + N_EDGES;

    // workspace carving (256B aligned)
    char* ws = (char*)d_ws;
    size_t off = 0;
    auto carve = [&](size_t bytes) {
        void* p = ws + off;
        off += (bytes + 255) & ~size_t(255);
        return p;
    };
    int*   deg      = (int*)carve(N_NODES * 4);
    int*   rowstart = (int*)carve(N_NODES * 4);
    int*   cursor   = (int*)carve(N_NODES * 4);
    int*   bsum     = (int*)carve(512 * 4);
    float* dinv     = (float*)carve(N_NODES * 4);
    float* zs1      = (float*)carve(N_NODES * 4);
    float* s        = (float*)carve(N_NODES * 4);
    int*   csr      = (int*)carve((size_t)N_EDGES * 4);           // 12.8 MB
    float* zs2      = (float*)carve((size_t)N_NODES * HID * 4);   // 12.8 MB
    float* zs3      = (float*)carve((size_t)N_NODES * HID * 4);   // 12.8 MB
    float* agg3     = zs2;   // zs2 dead after k_gather2 -> reuse

    const int gN   = (N_NODES + NB - 1) / NB;        // 391
    const int gE   = (N_EDGES + NB - 1) / NB;        // 12500
    const int gNF  = (N_NODES * HID + NB - 1) / NB;  // 12500

    k_zero_deg<<<gN, NB, 0, stream>>>(deg);
    k_deg<<<gE, NB, 0, stream>>>(dst, deg);
    k_scanA<<<gN, NB, 0, stream>>>(deg, bsum);
    k_scanB<<<1, 512, 0, stream>>>(bsum, gN);
    k_scanC<<<gN, NB, 0, stream>>>(deg, bsum, x, rowstart, cursor, dinv, zs1);
    k_scatter<<<gE, NB, 0, stream>>>(src, dst, cursor, csr);
    k_gather1<<<gN, NB, 0, stream>>>(rowstart, deg, csr, dinv, zs1, s);
    k_l1post<<<gNF, NB, 0, stream>>>(s, W1, b1, bn1g, bn1b, bn1m, bn1v, dinv, zs2);
    k_gather2<<<gNF, NB, 0, stream>>>(rowstart, deg, csr, dinv, zs2,
                                      W2, b2, bn2g, bn2b, bn2m, bn2v, zs3);
    k_gather3<<<gNF, NB, 0, stream>>>(rowstart, deg, csr, dinv, zs3, agg3);
    k_pool<<<N_GRAPHS, NB, 0, stream>>>(agg3, batch, W3, b3, out);
}

// Round 3
// 482.325 us; speedup vs baseline: 2.3557x; 1.6281x over previous
//
#include <hip/hip_runtime.h>

#define N_NODES 100000
#define N_EDGES 3200000
#define N_GRAPHS 1024
#define HID 32
#define BN_EPS 1e-5f
#define NB 256

#define NBKT 512
#define NPB 196                 // nodes per bucket; NBKT*NPB = 100352 >= N_NODES
#define PART_TILE 4096
#define PART_THREADS 256
#define PART_EPT (PART_TILE / PART_THREADS)   // 16

// ---------------- helpers ----------------

__device__ __forceinline__ int lbound(const int* __restrict__ a, int n, int key) {
    int lo = 0, hi = n;
    while (lo < hi) {
        int mid = (lo + hi) >> 1;
        if (a[mid] < key) lo = mid + 1; else hi = mid;
    }
    return lo;
}

// ---------------- CSR build (bucketed multisplit) ----------------

__global__ void k_zero(int* __restrict__ bhist) {
    bhist[threadIdx.x] = 0;
}

__global__ void k_hist(const int* __restrict__ dst, int* __restrict__ bhist) {
    __shared__ int h[NBKT];
    for (int i = threadIdx.x; i < NBKT; i += NB) h[i] = 0;
    __syncthreads();
    for (int e = blockIdx.x * NB + threadIdx.x; e < N_EDGES; e += gridDim.x * NB)
        atomicAdd(&h[dst[e] / NPB], 1);
    __syncthreads();
    for (int i = threadIdx.x; i < NBKT; i += NB)
        if (h[i]) atomicAdd(&bhist[i], h[i]);
}

// single block of NBKT threads: exclusive scan -> bstart, bcursor
__global__ void k_scan512(const int* __restrict__ bhist, int* __restrict__ bstart,
                          int* __restrict__ bcursor) {
    __shared__ int sm[NBKT];
    int t = threadIdx.x;
    int orig = bhist[t];
    sm[t] = orig;
    __syncthreads();
    for (int off = 1; off < NBKT; off <<= 1) {
        int v = (t >= off) ? sm[t - off] : 0;
        __syncthreads();
        sm[t] += v;
        __syncthreads();
    }
    int ex = sm[t] - orig;
    bstart[t] = ex;
    bcursor[t] = ex;
    if (t == NBKT - 1) bstart[NBKT] = sm[t];
}

// partition edges into bucket-major ebuf with chunked claims (coalesced-ish writes)
__global__ void k_partition(const int* __restrict__ src, const int* __restrict__ dst,
                            int* __restrict__ bcursor,
                            unsigned long long* __restrict__ ebuf) {
    __shared__ int lh[NBKT];
    __shared__ int lcur[NBKT];
    const int tile0 = blockIdx.x * PART_TILE;
    for (int i = threadIdx.x; i < NBKT; i += PART_THREADS) lh[i] = 0;
    __syncthreads();
    int s[PART_EPT], d[PART_EPT], bk[PART_EPT];
#pragma unroll
    for (int k = 0; k < PART_EPT; ++k) {
        int e = tile0 + k * PART_THREADS + threadIdx.x;
        bool ok = (e < N_EDGES);
        s[k] = ok ? src[e] : 0;
        d[k] = ok ? dst[e] : 0;
        bk[k] = ok ? (d[k] / NPB) : -1;
        if (ok) atomicAdd(&lh[bk[k]], 1);
    }
    __syncthreads();
    for (int i = threadIdx.x; i < NBKT; i += PART_THREADS)
        lcur[i] = lh[i] ? atomicAdd(&bcursor[i], lh[i]) : 0;
    __syncthreads();
#pragma unroll
    for (int k = 0; k < PART_EPT; ++k) {
        if (bk[k] >= 0) {
            int pos = atomicAdd(&lcur[bk[k]], 1);
            ebuf[pos] = ((unsigned long long)(unsigned)d[k] << 32) | (unsigned)s[k];
        }
    }
}

// per-bucket: node histogram -> rowstart/deg/dinv/zs1, then scatter csr
// (one block per bucket => csr writes confined to one XCD's L2)
__global__ void k_bucket(const int* __restrict__ bstart,
                         const unsigned long long* __restrict__ ebuf,
                         const float* __restrict__ x,
                         int* __restrict__ rowstart, int* __restrict__ deg,
                         float* __restrict__ dinv, float* __restrict__ zs1,
                         int* __restrict__ csr) {
    __shared__ int hist[NPB];
    __shared__ int sm[256];
    __shared__ int lcur[NPB];
    const int b = blockIdx.x;
    const int node0 = b * NPB;
    const int nn = N_NODES - node0;          // may exceed NPB or be <= 0
    const int elo = bstart[b], ehi = bstart[b + 1];
    const int t = threadIdx.x;

    for (int i = t; i < NPB; i += blockDim.x) hist[i] = 0;
    __syncthreads();
    for (int e = elo + t; e < ehi; e += blockDim.x) {
        int dv = (int)(ebuf[e] >> 32);
        atomicAdd(&hist[dv - node0], 1);
    }
    __syncthreads();
    // exclusive scan of hist (NPB <= 256)
    int orig = 0;
    if (t < 256) { orig = (t < NPB) ? hist[t] : 0; sm[t] = orig; }
    __syncthreads();
    for (int off = 1; off < 256; off <<= 1) {
        int v = 0;
        if (t < 256 && t >= off) v = sm[t - off];
        __syncthreads();
        if (t < 256) sm[t] += v;
        __syncthreads();
    }
    if (t < NPB) {
        int ex = sm[t] - orig;
        lcur[t] = ex;
        if (t < nn) {
            int node = node0 + t;
            rowstart[node] = elo + ex;
            deg[node] = orig;
            float di = rsqrtf((float)(orig + 1));   // +1 self-loop
            dinv[node] = di;
            zs1[node] = di * x[node];
        }
    }
    __syncthreads();
    for (int e = elo + t; e < ehi; e += blockDim.x) {
        unsigned long long pk = ebuf[e];
        int dv = (int)(pk >> 32) - node0;
        int pos = atomicAdd(&lcur[dv], 1);
        csr[elo + pos] = (int)(pk & 0xffffffffu);
    }
}

// ---------------- layer 1 (scalar feature) ----------------

__global__ void k_gather1(const int* __restrict__ rowstart, const int* __restrict__ deg,
                          const int* __restrict__ csr, const float* __restrict__ dinv,
                          const float* __restrict__ zs1, float* __restrict__ s) {
    int v = blockIdx.x * NB + threadIdx.x;
    if (v < N_NODES) {
        int lo = rowstart[v], n = deg[v];
        float acc = zs1[v];
        for (int j = 0; j < n; ++j) acc += zs1[csr[lo + j]];
        s[v] = dinv[v] * acc;
    }
}

// zs2 = dinv * relu(bn1(s*W1 + b1))
__global__ void k_l1post(const float* __restrict__ s, const float* __restrict__ W1,
                         const float* __restrict__ b1, const float* __restrict__ g,
                         const float* __restrict__ bb, const float* __restrict__ m,
                         const float* __restrict__ v, const float* __restrict__ dinv,
                         float* __restrict__ zs2) {
    int t = blockIdx.x * NB + threadIdx.x;
    if (t < N_NODES * HID) {
        int i = t >> 5, f = t & 31;
        float h = s[i] * W1[f] + b1[f];
        float scale = g[f] * rsqrtf(v[f] + BN_EPS);
        float z = fmaxf((h - m[f]) * scale + bb[f], 0.0f);
        zs2[t] = dinv[i] * z;
    }
}

// ---------------- layer 2: gather + fused matmul/BN/ReLU/prescale ----------------

__global__ void k_gather2(const int* __restrict__ rowstart, const int* __restrict__ deg,
                          const int* __restrict__ csr, const float* __restrict__ dinv,
                          const float* __restrict__ zs2, const float* __restrict__ W2,
                          const float* __restrict__ b2, const float* __restrict__ g2,
                          const float* __restrict__ bb2, const float* __restrict__ m2,
                          const float* __restrict__ v2, float* __restrict__ zs3) {
    __shared__ float Ws[HID * HID];
    __shared__ float rowbuf[NB / HID][HID + 1];
    for (int k = threadIdx.x; k < HID * HID; k += NB) Ws[k] = W2[k];

    int t = blockIdx.x * NB + threadIdx.x;
    int v = t >> 5, f = t & 31, r = threadIdx.x >> 5;
    float acc = 0.0f, di = 0.0f;
    if (v < N_NODES) {
        di = dinv[v];
        int lo = rowstart[v], n = deg[v];
        acc = zs2[v * HID + f];
        for (int j = 0; j < n; ++j) {
            int u = csr[lo + j];
            acc += zs2[u * HID + f];
        }
        acc *= di;
    }
    rowbuf[r][f] = acc;
    __syncthreads();
    if (v < N_NODES) {
        float h = b2[f];
#pragma unroll
        for (int k = 0; k < HID; ++k) h += rowbuf[r][k] * Ws[k * HID + f];
        float scale = g2[f] * rsqrtf(v2[f] + BN_EPS);
        float z = fmaxf((h - m2[f]) * scale + bb2[f], 0.0f);
        zs3[v * HID + f] = di * z;
    }
}

// ---------------- layer 3: gather only ----------------

__global__ void k_gather3(const int* __restrict__ rowstart, const int* __restrict__ deg,
                          const int* __restrict__ csr, const float* __restrict__ dinv,
                          const float* __restrict__ zs3, float* __restrict__ agg3) {
    int t = blockIdx.x * NB + threadIdx.x;
    int v = t >> 5, f = t & 31;
    if (v < N_NODES) {
        int lo = rowstart[v], n = deg[v];
        float acc = zs3[v * HID + f];
        for (int j = 0; j < n; ++j) {
            int u = csr[lo + j];
            acc += zs3[u * HID + f];
        }
        agg3[v * HID + f] = dinv[v] * acc;
    }
}

// ---------------- pool: block per graph, mean then matmul W3 ----------------

__global__ void k_pool(const float* __restrict__ agg3, const int* __restrict__ batch,
                       const float* __restrict__ W3, const float* __restrict__ b3,
                       float* __restrict__ out) {
    __shared__ float Ws[HID * HID];
    __shared__ float part[NB / HID][HID + 1];
    __shared__ float mrow[HID];
    int g = blockIdx.x;
    for (int k = threadIdx.x; k < HID * HID; k += NB) Ws[k] = W3[k];

    int lo = lbound(batch, N_NODES, g);
    int hi = lbound(batch, N_NODES, g + 1);

    int r = threadIdx.x >> 5, f = threadIdx.x & 31;
    float acc = 0.0f;
    for (int i = lo + r; i < hi; i += NB / HID) acc += agg3[i * HID + f];
    part[r][f] = acc;
    __syncthreads();
    if (threadIdx.x < HID) {
        float srow = 0.0f;
#pragma unroll
        for (int k = 0; k < NB / HID; ++k) srow += part[k][threadIdx.x];
        float c = (float)(hi - lo);
        mrow[threadIdx.x] = (hi > lo) ? srow / c : 0.0f;
    }
    __syncthreads();
    if (threadIdx.x < HID) {
        int ff = threadIdx.x;
        float o = 0.0f;
        if (hi > lo) {
            o = b3[ff];
#pragma unroll
            for (int k = 0; k < HID; ++k) o += mrow[k] * Ws[k * HID + ff];
        }
        out[g * HID + ff] = o;
    }
}

// ---------------- launch ----------------

extern "C" void kernel_launch(void* const* d_in, const int* in_sizes, int n_in,
                              void* d_out, int out_size, void* d_ws, size_t ws_size,
                              hipStream_t stream) {
    const float* x     = (const float*)d_in[0];
    const int*   eidx  = (const int*)d_in[1];     // [2, E]: row0 = src, row1 = dst
    const int*   batch = (const int*)d_in[2];
    const float* W1    = (const float*)d_in[3];
    const float* b1    = (const float*)d_in[4];
    const float* bn1g  = (const float*)d_in[5];
    const float* bn1b  = (const float*)d_in[6];
    const float* bn1m  = (const float*)d_in[7];
    const float* bn1v  = (const float*)d_in[8];
    const float* W2    = (const float*)d_in[9];
    const float* b2    = (const float*)d_in[10];
    const float* bn2g  = (const float*)d_in[11];
    const float* bn2b  = (const float*)d_in[12];
    const float* bn2m  = (const float*)d_in[13];
    const float* bn2v  = (const float*)d_in[14];
    const float* W3    = (const float*)d_in[15];
    const float* b3    = (const float*)d_in[16];
    float* out = (float*)d_out;

    const int* src = eidx;
    const int* dst = eidx + N_EDGES;

    // workspace carving (256B aligned)
    char* ws = (char*)d_ws;
    size_t off = 0;
    auto carve = [&](size_t bytes) {
        void* p = ws + off;
        off += (bytes + 255) & ~size_t(255);
        return p;
    };
    int*   bhist    = (int*)carve(NBKT * 4);
    int*   bstart   = (int*)carve((NBKT + 1) * 4);
    int*   bcursor  = (int*)carve(NBKT * 4);
    int*   rowstart = (int*)carve(N_NODES * 4);
    int*   deg      = (int*)carve(N_NODES * 4);
    float* dinv     = (float*)carve(N_NODES * 4);
    float* zs1      = (float*)carve(N_NODES * 4);
    float* s        = (float*)carve(N_NODES * 4);
    int*   csr      = (int*)carve((size_t)N_EDGES * 4);            // 12.8 MB
    // ebuf (25.6 MB) aliases zs2+zs3: ebuf dead after k_bucket, zs2/zs3 born after
    char*  region   = (char*)carve((size_t)N_EDGES * 8);
    unsigned long long* ebuf = (unsigned long long*)region;
    float* zs2      = (float*)region;
    float* zs3      = (float*)(region + (size_t)N_NODES * HID * 4);
    float* agg3     = zs2;   // zs2 dead after k_gather2 -> reuse

    const int gN   = (N_NODES + NB - 1) / NB;           // 391
    const int gNF  = (N_NODES * HID + NB - 1) / NB;     // 12500
    const int gPart = (N_EDGES + PART_TILE - 1) / PART_TILE;  // 782

    k_zero<<<1, NBKT, 0, stream>>>(bhist);
    k_hist<<<1024, NB, 0, stream>>>(dst, bhist);
    k_scan512<<<1, NBKT, 0, stream>>>(bhist, bstart, bcursor);
    k_partition<<<gPart, PART_THREADS, 0, stream>>>(src, dst, bcursor, ebuf);
    k_bucket<<<NBKT, 512, 0, stream>>>(bstart, ebuf, x, rowstart, deg, dinv, zs1, csr);
    k_gather1<<<gN, NB, 0, stream>>>(rowstart, deg, csr, dinv, zs1, s);
    k_l1post<<<gNF, NB, 0, stream>>>(s, W1, b1, bn1g, bn1b, bn1m, bn1v, dinv, zs2);
    k_gather2<<<gNF, NB, 0, stream>>>(rowstart, deg, csr, dinv, zs2,
                                      W2, b2, bn2g, bn2b, bn2m, bn2v, zs3);
    k_gather3<<<gNF, NB, 0, stream>>>(rowstart, deg, csr, dinv, zs3, agg3);
    k_pool<<<N_GRAPHS, NB, 0, stream>>>(agg3, batch, W3, b3, out);
}

// Round 4
// 282.446 us; speedup vs baseline: 4.0227x; 1.7077x over previous
//
#include <hip/hip_runtime.h>

#define N_NODES 100000
#define N_EDGES 3200000
#define N_GRAPHS 1024
#define HID 32
#define BN_EPS 1e-5f
#define NB 256

#define NBKT 512
#define NPB 196                 // nodes per bucket; NBKT*NPB = 100352 >= N_NODES
#define PART_TILE 4096
#define PART_THREADS 256
#define PART_EPT (PART_TILE / PART_THREADS)   // 16

// ---------------- helpers ----------------

__device__ __forceinline__ int lbound(const int* __restrict__ a, int n, int key) {
    int lo = 0, hi = n;
    while (lo < hi) {
        int mid = (lo + hi) >> 1;
        if (a[mid] < key) lo = mid + 1; else hi = mid;
    }
    return lo;
}

__device__ __forceinline__ float bf2f(unsigned short h) {
    return __uint_as_float((unsigned)h << 16);
}
__device__ __forceinline__ unsigned short f2bf(float x) {   // round-to-nearest-even
    unsigned u = __float_as_uint(x);
    u += 0x7fffu + ((u >> 16) & 1u);
    return (unsigned short)(u >> 16);
}

// ---------------- CSR build (bucketed multisplit) ----------------

__global__ void k_zero(int* __restrict__ bhist) {
    bhist[threadIdx.x] = 0;
}

__global__ void k_hist(const int* __restrict__ dst, int* __restrict__ bhist) {
    __shared__ int h[NBKT];
    for (int i = threadIdx.x; i < NBKT; i += NB) h[i] = 0;
    __syncthreads();
    for (int e = blockIdx.x * NB + threadIdx.x; e < N_EDGES; e += gridDim.x * NB)
        atomicAdd(&h[dst[e] / NPB], 1);
    __syncthreads();
    for (int i = threadIdx.x; i < NBKT; i += NB)
        if (h[i]) atomicAdd(&bhist[i], h[i]);
}

// single block of NBKT threads: exclusive scan -> bstart, bcursor
__global__ void k_scan512(const int* __restrict__ bhist, int* __restrict__ bstart,
                          int* __restrict__ bcursor) {
    __shared__ int sm[NBKT];
    int t = threadIdx.x;
    int orig = bhist[t];
    sm[t] = orig;
    __syncthreads();
    for (int off = 1; off < NBKT; off <<= 1) {
        int v = (t >= off) ? sm[t - off] : 0;
        __syncthreads();
        sm[t] += v;
        __syncthreads();
    }
    int ex = sm[t] - orig;
    bstart[t] = ex;
    bcursor[t] = ex;
    if (t == NBKT - 1) bstart[NBKT] = sm[t];
}

// partition edges into bucket-major ebuf with chunked claims
__global__ void k_partition(const int* __restrict__ src, const int* __restrict__ dst,
                            int* __restrict__ bcursor,
                            unsigned long long* __restrict__ ebuf) {
    __shared__ int lh[NBKT];
    __shared__ int lcur[NBKT];
    const int tile0 = blockIdx.x * PART_TILE;
    for (int i = threadIdx.x; i < NBKT; i += PART_THREADS) lh[i] = 0;
    __syncthreads();
    int s[PART_EPT], d[PART_EPT], bk[PART_EPT];
#pragma unroll
    for (int k = 0; k < PART_EPT; ++k) {
        int e = tile0 + k * PART_THREADS + threadIdx.x;
        bool ok = (e < N_EDGES);
        s[k] = ok ? src[e] : 0;
        d[k] = ok ? dst[e] : 0;
        bk[k] = ok ? (d[k] / NPB) : -1;
        if (ok) atomicAdd(&lh[bk[k]], 1);
    }
    __syncthreads();
    for (int i = threadIdx.x; i < NBKT; i += PART_THREADS)
        lcur[i] = lh[i] ? atomicAdd(&bcursor[i], lh[i]) : 0;
    __syncthreads();
#pragma unroll
    for (int k = 0; k < PART_EPT; ++k) {
        if (bk[k] >= 0) {
            int pos = atomicAdd(&lcur[bk[k]], 1);
            ebuf[pos] = ((unsigned long long)(unsigned)d[k] << 32) | (unsigned)s[k];
        }
    }
}

// per-bucket: node histogram -> rowstart/deg/dinv/zs1, then scatter csr
__global__ void k_bucket(const int* __restrict__ bstart,
                         const unsigned long long* __restrict__ ebuf,
                         const float* __restrict__ x,
                         int* __restrict__ rowstart, int* __restrict__ deg,
                         float* __restrict__ dinv, float* __restrict__ zs1,
                         int* __restrict__ csr) {
    __shared__ int hist[NPB];
    __shared__ int sm[256];
    __shared__ int lcur[NPB];
    const int b = blockIdx.x;
    const int node0 = b * NPB;
    const int nn = N_NODES - node0;
    const int elo = bstart[b], ehi = bstart[b + 1];
    const int t = threadIdx.x;

    for (int i = t; i < NPB; i += blockDim.x) hist[i] = 0;
    __syncthreads();
    for (int e = elo + t; e < ehi; e += blockDim.x) {
        int dv = (int)(ebuf[e] >> 32);
        atomicAdd(&hist[dv - node0], 1);
    }
    __syncthreads();
    int orig = 0;
    if (t < 256) { orig = (t < NPB) ? hist[t] : 0; sm[t] = orig; }
    __syncthreads();
    for (int off = 1; off < 256; off <<= 1) {
        int v = 0;
        if (t < 256 && t >= off) v = sm[t - off];
        __syncthreads();
        if (t < 256) sm[t] += v;
        __syncthreads();
    }
    if (t < NPB) {
        int ex = sm[t] - orig;
        lcur[t] = ex;
        if (t < nn) {
            int node = node0 + t;
            rowstart[node] = elo + ex;
            deg[node] = orig;
            float di = rsqrtf((float)(orig + 1));
            dinv[node] = di;
            zs1[node] = di * x[node];
        }
    }
    __syncthreads();
    for (int e = elo + t; e < ehi; e += blockDim.x) {
        unsigned long long pk = ebuf[e];
        int dv = (int)(pk >> 32) - node0;
        int pos = atomicAdd(&lcur[dv], 1);
        csr[elo + pos] = (int)(pk & 0xffffffffu);
    }
}

// ---------------- layer 1 (scalar feature) ----------------

__global__ void k_gather1(const int* __restrict__ rowstart, const int* __restrict__ deg,
                          const int* __restrict__ csr, const float* __restrict__ dinv,
                          const float* __restrict__ zs1, float* __restrict__ s) {
    int v = blockIdx.x * NB + threadIdx.x;
    if (v < N_NODES) {
        int lo = rowstart[v], n = deg[v];
        float acc = zs1[v];
        int j = 0;
        for (; j + 4 <= n; j += 4) {
            int u0 = csr[lo + j], u1 = csr[lo + j + 1];
            int u2 = csr[lo + j + 2], u3 = csr[lo + j + 3];
            float a0 = zs1[u0], a1 = zs1[u1], a2 = zs1[u2], a3 = zs1[u3];
            acc += (a0 + a1) + (a2 + a3);
        }
        for (; j < n; ++j) acc += zs1[csr[lo + j]];
        s[v] = dinv[v] * acc;
    }
}

// zs2h = bf16(dinv * relu(bn1(s*W1 + b1)))
__global__ void k_l1post(const float* __restrict__ s, const float* __restrict__ W1,
                         const float* __restrict__ b1, const float* __restrict__ g,
                         const float* __restrict__ bb, const float* __restrict__ m,
                         const float* __restrict__ v, const float* __restrict__ dinv,
                         unsigned short* __restrict__ zs2h) {
    int t = blockIdx.x * NB + threadIdx.x;
    if (t < N_NODES * HID) {
        int i = t >> 5, f = t & 31;
        float h = s[i] * W1[f] + b1[f];
        float scale = g[f] * rsqrtf(v[f] + BN_EPS);
        float z = fmaxf((h - m[f]) * scale + bb[f], 0.0f);
        zs2h[t] = f2bf(dinv[i] * z);
    }
}

// ---------------- layer 2: gather(bf16) + fused matmul/BN/ReLU/prescale ----------------

__global__ void k_gather2(const int* __restrict__ rowstart, const int* __restrict__ deg,
                          const int* __restrict__ csr, const float* __restrict__ dinv,
                          const unsigned short* __restrict__ zs2h,
                          const float* __restrict__ W2,
                          const float* __restrict__ b2, const float* __restrict__ g2,
                          const float* __restrict__ bb2, const float* __restrict__ m2,
                          const float* __restrict__ v2, unsigned short* __restrict__ zs3h) {
    __shared__ float Ws[HID * HID];
    __shared__ float rowbuf[NB / HID][HID + 1];
    for (int k = threadIdx.x; k < HID * HID; k += NB) Ws[k] = W2[k];

    int t = blockIdx.x * NB + threadIdx.x;
    int v = t >> 5, f = t & 31, r = threadIdx.x >> 5;
    float acc = 0.0f, di = 0.0f;
    if (v < N_NODES) {
        di = dinv[v];
        int lo = rowstart[v], n = deg[v];
        acc = bf2f(zs2h[v * HID + f]);
        int j = 0;
        for (; j + 4 <= n; j += 4) {
            int u0 = csr[lo + j], u1 = csr[lo + j + 1];
            int u2 = csr[lo + j + 2], u3 = csr[lo + j + 3];
            float a0 = bf2f(zs2h[u0 * HID + f]);
            float a1 = bf2f(zs2h[u1 * HID + f]);
            float a2 = bf2f(zs2h[u2 * HID + f]);
            float a3 = bf2f(zs2h[u3 * HID + f]);
            acc += (a0 + a1) + (a2 + a3);
        }
        for (; j < n; ++j) acc += bf2f(zs2h[csr[lo + j] * HID + f]);
        acc *= di;
    }
    rowbuf[r][f] = acc;
    __syncthreads();
    if (v < N_NODES) {
        float h = b2[f];
#pragma unroll
        for (int k = 0; k < HID; ++k) h += rowbuf[r][k] * Ws[k * HID + f];
        float scale = g2[f] * rsqrtf(v2[f] + BN_EPS);
        float z = fmaxf((h - m2[f]) * scale + bb2[f], 0.0f);
        zs3h[v * HID + f] = f2bf(di * z);
    }
}

// ---------------- layer 3: gather(bf16) only ----------------

__global__ void k_gather3(const int* __restrict__ rowstart, const int* __restrict__ deg,
                          const int* __restrict__ csr, const float* __restrict__ dinv,
                          const unsigned short* __restrict__ zs3h,
                          float* __restrict__ agg3) {
    int t = blockIdx.x * NB + threadIdx.x;
    int v = t >> 5, f = t & 31;
    if (v < N_NODES) {
        int lo = rowstart[v], n = deg[v];
        float acc = bf2f(zs3h[v * HID + f]);
        int j = 0;
        for (; j + 4 <= n; j += 4) {
            int u0 = csr[lo + j], u1 = csr[lo + j + 1];
            int u2 = csr[lo + j + 2], u3 = csr[lo + j + 3];
            float a0 = bf2f(zs3h[u0 * HID + f]);
            float a1 = bf2f(zs3h[u1 * HID + f]);
            float a2 = bf2f(zs3h[u2 * HID + f]);
            float a3 = bf2f(zs3h[u3 * HID + f]);
            acc += (a0 + a1) + (a2 + a3);
        }
        for (; j < n; ++j) acc += bf2f(zs3h[csr[lo + j] * HID + f]);
        agg3[v * HID + f] = dinv[v] * acc;
    }
}

// ---------------- pool: block per graph, mean then matmul W3 ----------------

__global__ void k_pool(const float* __restrict__ agg3, const int* __restrict__ batch,
                       const float* __restrict__ W3, const float* __restrict__ b3,
                       float* __restrict__ out) {
    __shared__ float Ws[HID * HID];
    __shared__ float part[NB / HID][HID + 1];
    __shared__ float mrow[HID];
    int g = blockIdx.x;
    for (int k = threadIdx.x; k < HID * HID; k += NB) Ws[k] = W3[k];

    int lo = lbound(batch, N_NODES, g);
    int hi = lbound(batch, N_NODES, g + 1);

    int r = threadIdx.x >> 5, f = threadIdx.x & 31;
    float acc = 0.0f;
    for (int i = lo + r; i < hi; i += NB / HID) acc += agg3[i * HID + f];
    part[r][f] = acc;
    __syncthreads();
    if (threadIdx.x < HID) {
        float srow = 0.0f;
#pragma unroll
        for (int k = 0; k < NB / HID; ++k) srow += part[k][threadIdx.x];
        float c = (float)(hi - lo);
        mrow[threadIdx.x] = (hi > lo) ? srow / c : 0.0f;
    }
    __syncthreads();
    if (threadIdx.x < HID) {
        int ff = threadIdx.x;
        float o = 0.0f;
        if (hi > lo) {
            o = b3[ff];
#pragma unroll
            for (int k = 0; k < HID; ++k) o += mrow[k] * Ws[k * HID + ff];
        }
        out[g * HID + ff] = o;
    }
}

// ---------------- launch ----------------

extern "C" void kernel_launch(void* const* d_in, const int* in_sizes, int n_in,
                              void* d_out, int out_size, void* d_ws, size_t ws_size,
                              hipStream_t stream) {
    const float* x     = (const float*)d_in[0];
    const int*   eidx  = (const int*)d_in[1];     // [2, E]: row0 = src, row1 = dst
    const int*   batch = (const int*)d_in[2];
    const float* W1    = (const float*)d_in[3];
    const float* b1    = (const float*)d_in[4];
    const float* bn1g  = (const float*)d_in[5];
    const float* bn1b  = (const float*)d_in[6];
    const float* bn1m  = (const float*)d_in[7];
    const float* bn1v  = (const float*)d_in[8];
    const float* W2    = (const float*)d_in[9];
    const float* b2    = (const float*)d_in[10];
    const float* bn2g  = (const float*)d_in[11];
    const float* bn2b  = (const float*)d_in[12];
    const float* bn2m  = (const float*)d_in[13];
    const float* bn2v  = (const float*)d_in[14];
    const float* W3    = (const float*)d_in[15];
    const float* b3    = (const float*)d_in[16];
    float* out = (float*)d_out;

    const int* src = eidx;
    const int* dst = eidx + N_EDGES;

    // workspace carving (256B aligned)
    char* ws = (char*)d_ws;
    size_t off = 0;
    auto carve = [&](size_t bytes) {
        void* p = ws + off;
        off += (bytes + 255) & ~size_t(255);
        return p;
    };
    int*   bhist    = (int*)carve(NBKT * 4);
    int*   bstart   = (int*)carve((NBKT + 1) * 4);
    int*   bcursor  = (int*)carve(NBKT * 4);
    int*   rowstart = (int*)carve(N_NODES * 4);
    int*   deg      = (int*)carve(N_NODES * 4);
    float* dinv     = (float*)carve(N_NODES * 4);
    float* zs1      = (float*)carve(N_NODES * 4);
    float* s        = (float*)carve(N_NODES * 4);
    int*   csr      = (int*)carve((size_t)N_EDGES * 4);            // 12.8 MB
    // 25.6 MB region: ebuf dead after k_bucket; then zs2h(6.4) | zs3h(6.4) | agg3(12.8)
    char*  region   = (char*)carve((size_t)N_EDGES * 8);
    unsigned long long* ebuf = (unsigned long long*)region;
    unsigned short* zs2h = (unsigned short*)region;
    unsigned short* zs3h = (unsigned short*)(region + (size_t)N_NODES * HID * 2);
    float* agg3          = (float*)(region + (size_t)N_NODES * HID * 4);

    const int gN   = (N_NODES + NB - 1) / NB;           // 391
    const int gNF  = (N_NODES * HID + NB - 1) / NB;     // 12500
    const int gPart = (N_EDGES + PART_TILE - 1) / PART_TILE;  // 782

    k_zero<<<1, NBKT, 0, stream>>>(bhist);
    k_hist<<<1024, NB, 0, stream>>>(dst, bhist);
    k_scan512<<<1, NBKT, 0, stream>>>(bhist, bstart, bcursor);
    k_partition<<<gPart, PART_THREADS, 0, stream>>>(src, dst, bcursor, ebuf);
    k_bucket<<<NBKT, 512, 0, stream>>>(bstart, ebuf, x, rowstart, deg, dinv, zs1, csr);
    k_gather1<<<gN, NB, 0, stream>>>(rowstart, deg, csr, dinv, zs1, s);
    k_l1post<<<gNF, NB, 0, stream>>>(s, W1, b1, bn1g, bn1b, bn1m, bn1v, dinv, zs2h);
    k_gather2<<<gNF, NB, 0, stream>>>(rowstart, deg, csr, dinv, zs2h,
                                      W2, b2, bn2g, bn2b, bn2m, bn2v, zs3h);
    k_gather3<<<gNF, NB, 0, stream>>>(rowstart, deg, csr, dinv, zs3h, agg3);
    k_pool<<<N_GRAPHS, NB, 0, stream>>>(agg3, batch, W3, b3, out);
}